// Round 2
// baseline (1544.456 us; speedup 1.0000x reference)
//
#include <hip/hip_runtime.h>

#define NN 128
#define NE 4096
#define DD 130
#define HH 64
#define KK1 8320   // D*H
#define CC 256     // ea-value chunks
#define KHALF 4160 // KK1/2

// workspace layout (float offsets)
#define OFF_AGG1 0            // 8192
#define OFF_AGG2 8192         // 8192
#define ZERO_F   16384        // floats zeroed each call (agg1+agg2)
#define OFF_CNT  16384        // 128 (fully written by k_count)
#define OFF_XR1  16512        // 8192
#define OFF_H1   24704        // 8192
#define OFF_HB2  32896        // 8192
#define OFF_HR2  41088        // 8192
#define OFF_H2   49280        // 8192
#define OFF_G2   57472        // 524288
#define OFF_PD   581760       // 2 halves * CC * 8320 = 4259840 (per-half prefix states)
#define OFF_QD   4841600      // 4259840
#define OFF_INT  9101440      // ints: e_off[257], k_off[257], e_idx[4096], k_idx[8320]

// Event bin for threshold t_k = -c/a within [0,1): chunk in which k flips.
// a>0: activates when ea crosses t upward. a<0: deactivates.
__device__ __forceinline__ int event_bin(float a, float c) {
  if (a > 0.f) {
    if (c <= 0.f) { float tt = -c / a; if (tt < 1.f) return (int)(tt * 256.0f); }
  } else if (a < 0.f) {
    if (c > 0.f) { float tt = -c / a; if (tt < 1.f) return (int)ceilf(tt * 256.0f) - 1; }
  }
  return -1;
}

// ---------- counts, chunk lists for edges and k-events ----------
__global__ __launch_bounds__(256) void k_count(const int* __restrict__ ei,
                                               const float* __restrict__ eattr,
                                               const float* __restrict__ W1a,
                                               const float* __restrict__ b1a,
                                               int* __restrict__ e_off,
                                               int* __restrict__ k_off,
                                               int* __restrict__ e_idx,
                                               int* __restrict__ k_idx,
                                               float* __restrict__ cnt) {
  __shared__ int ec[CC], kc[CC], cd[NN];
  __shared__ int eo[CC + 1], ko[CC + 1];
  int t = threadIdx.x;
  ec[t] = 0; kc[t] = 0;
  if (t < NN) cd[t] = 0;
  __syncthreads();
  for (int e = t; e < NE; e += 256) {
    atomicAdd(&cd[ei[NE + e]], 1);
    int c = (int)(eattr[e] * 256.0f); c = c < 0 ? 0 : (c > CC - 1 ? CC - 1 : c);
    atomicAdd(&ec[c], 1);
  }
  for (int k = t; k < KK1; k += 256) {
    int b = event_bin(W1a[k], b1a[k]);
    if (b >= 0) atomicAdd(&kc[b], 1);
  }
  __syncthreads();
  if (t == 0) {
    int r = 0;
    for (int c = 0; c < CC; c++) { eo[c] = r; r += ec[c]; } eo[CC] = r;
    r = 0;
    for (int c = 0; c < CC; c++) { ko[c] = r; r += kc[c]; } ko[CC] = r;
  }
  __syncthreads();
  if (t < NN) cnt[t] = (float)cd[t];
  e_off[t] = eo[t]; k_off[t] = ko[t];
  if (t == 0) { e_off[CC] = eo[CC]; k_off[CC] = ko[CC]; }
  ec[t] = eo[t]; kc[t] = ko[t];   // cursors
  __syncthreads();
  for (int e = t; e < NE; e += 256) {
    int c = (int)(eattr[e] * 256.0f); c = c < 0 ? 0 : (c > CC - 1 ? CC - 1 : c);
    int p = atomicAdd(&ec[c], 1);
    e_idx[p] = e;
  }
  for (int k = t; k < KK1; k += 256) {
    int b = event_bin(W1a[k], b1a[k]);
    if (b >= 0) { int p = atomicAdd(&kc[b], 1); k_idx[p] = k; }
  }
}

// ---------- xr1 = x @ Wr1 ----------
__global__ __launch_bounds__(256) void k_small1x(const float* __restrict__ x,
                                                 const float* __restrict__ Wr1,
                                                 float* __restrict__ xr1) {
  int f = blockIdx.x * 256 + threadIdx.x;   // < 8192
  int n = f >> 6, o = f & 63;
  float a = 0.f;
  for (int i = 0; i < DD; i++) a = fmaf(x[n * DD + i], Wr1[i * HH + o], a);
  xr1[f] = a;
}

// ---------- stream W1b once; per-half boundary-prefix states into PD/QD ----------
// PD[half][c][col] = sum over this half's k of 1[k active at v_c] * W1a[k]*W1b[k,col]
__global__ __launch_bounds__(256) void k_build(const float* __restrict__ W1a,
                                               const float* __restrict__ b1a,
                                               const float* __restrict__ W1b,
                                               float* __restrict__ PD,
                                               float* __restrict__ QD) {
  __shared__ float Pd[CC * 64];
  __shared__ float Qd[CC * 64];
  __shared__ float segP[4 * 64], segQ[4 * 64];
  int t = threadIdx.x;
  int j0 = blockIdx.x * 64;
  int half = blockIdx.y;
  for (int i = t; i < CC * 64; i += 256) { Pd[i] = 0.f; Qd[i] = 0.f; }
  __syncthreads();
  int o = t & 63;
  int r = t >> 6;
  long col = j0 + o;
  int kbase = half * KHALF;
  for (int k0 = kbase; k0 < kbase + KHALF; k0 += 64) {
    float w[16];
#pragma unroll
    for (int j = 0; j < 16; j++) w[j] = W1b[(long)(k0 + r + 4 * j) * KK1 + col];
#pragma unroll
    for (int j = 0; j < 16; j++) {
      int k = k0 + r + 4 * j;
      float a = W1a[k], c2 = b1a[k];
      if (a > 0.f) {
        int b;
        if (c2 > 0.f) b = 0;
        else { int eb = event_bin(a, c2); b = (eb >= 0) ? eb + 1 : CC; }
        if (b < CC) {
          atomicAdd(&Pd[b * 64 + o], a * w[j]);
          atomicAdd(&Qd[b * 64 + o], c2 * w[j]);
        }
      } else if (a < 0.f) {
        if (c2 > 0.f) {
          atomicAdd(&Pd[o], a * w[j]);
          atomicAdd(&Qd[o], c2 * w[j]);
          int eb = event_bin(a, c2);
          if (eb >= 0 && eb + 1 < CC) {
            atomicAdd(&Pd[(eb + 1) * 64 + o], -a * w[j]);
            atomicAdd(&Qd[(eb + 1) * 64 + o], -c2 * w[j]);
          }
        }
      } else {
        if (c2 > 0.f) atomicAdd(&Qd[o], c2 * w[j]);
      }
    }
  }
  __syncthreads();
  // in-LDS prefix over the 256 bins (segmented: 4 segs of 64)
  {
    float s = 0.f;
    for (int c = r * 64; c < r * 64 + 64; c++) { s += Pd[c * 64 + o]; Pd[c * 64 + o] = s; }
    segP[r * 64 + o] = s;
    float s2 = 0.f;
    for (int c = r * 64; c < r * 64 + 64; c++) { s2 += Qd[c * 64 + o]; Qd[c * 64 + o] = s2; }
    segQ[r * 64 + o] = s2;
  }
  __syncthreads();
  {
    float off = 0.f, off2 = 0.f;
    for (int p = 0; p < r; p++) { off += segP[p * 64 + o]; off2 += segQ[p * 64 + o]; }
    if (r > 0)
      for (int c = r * 64; c < r * 64 + 64; c++) { Pd[c * 64 + o] += off; Qd[c * 64 + o] += off2; }
  }
  __syncthreads();
  long base = (long)half * CC * KK1;
  for (int i = t; i < CC * 64; i += 256) {
    int c = i >> 6, oo = i & 63;
    PD[base + (long)c * KK1 + j0 + oo] = Pd[i];
    QD[base + (long)c * KK1 + j0 + oo] = Qd[i];
  }
}

// ---------- per-chunk sweep: events update P,Q in LDS; edges -> agg1 atomically ----------
#define EC 192
#define KC 128
__global__ __launch_bounds__(256) void k_sweep(const float* __restrict__ PD,
                                               const float* __restrict__ QD,
                                               const float* __restrict__ b1b,
                                               const float* __restrict__ W1a,
                                               const float* __restrict__ b1a,
                                               const float* __restrict__ W1b,
                                               const float* __restrict__ x,
                                               const float* __restrict__ eattr,
                                               const int* __restrict__ ei,
                                               const int* __restrict__ e_off,
                                               const int* __restrict__ e_idx,
                                               const int* __restrict__ k_off,
                                               const int* __restrict__ k_idx,
                                               float* __restrict__ agg1) {
  __shared__ float Pl[KK1], Ql[KK1];
  __shared__ float eas[EC], eas_r[EC];
  __shared__ int eix[EC], eix_r[EC];
  __shared__ float tks[KC], tks_r[KC];
  __shared__ int kix[KC], kix_r[KC];
  int c = blockIdx.x, t = threadIdx.x;
  int eb = e_off[c], ne = e_off[c + 1] - eb; if (ne > EC) ne = EC;
  int kb = k_off[c], nk = k_off[c + 1] - kb; if (nk > KC) nk = KC;
  for (int j = t; j < KK1; j += 256) {
    Pl[j] = PD[(long)c * KK1 + j] + PD[((long)CC + c) * KK1 + j];
    Ql[j] = QD[(long)c * KK1 + j] + QD[((long)CC + c) * KK1 + j] + b1b[j];
  }
  if (t < ne) { int e = e_idx[eb + t]; eix_r[t] = e; eas_r[t] = eattr[e]; }
  if (t < nk) {
    int k = k_idx[kb + t];
    kix_r[t] = k;
    tks_r[t] = -b1a[k] / W1a[k];
  }
  __syncthreads();
  if (t < ne) {  // rank sort edges by ea
    float key = eas_r[t]; int rk = 0;
    for (int j = 0; j < ne; j++) { float kj = eas_r[j]; rk += (kj < key) || (kj == key && j < t); }
    eas[rk] = key; eix[rk] = eix_r[t];
  }
  if (t < nk) {  // rank sort events by threshold
    float key = tks_r[t]; int rk = 0;
    for (int j = 0; j < nk; j++) { float kj = tks_r[j]; rk += (kj < key) || (kj == key && j < t); }
    tks[rk] = key; kix[rk] = kix_r[t];
  }
  __syncthreads();
  if (ne == 0) return;
  int ie = 0, ik = 0;
  int q = t >> 6, o = t & 63;
  while (ie < ne) {
    if (ik < nk && tks[ik] < eas[ie]) {
      int k = kix[ik];
      float a = W1a[k], c2 = b1a[k];
      float sa = (a > 0.f) ? a : -a;
      float sc = (a > 0.f) ? c2 : -c2;
      __syncthreads();                    // prior batch reads of Pl/Ql complete
      for (int j = t; j < KK1; j += 256) {
        float w = W1b[(long)k * KK1 + j];
        Pl[j] = fmaf(sa, w, Pl[j]);
        Ql[j] = fmaf(sc, w, Ql[j]);
      }
      __syncthreads();
      ik++;
    } else {
      int m = 1;
      while (ie + m < ne && (ik >= nk || eas[ie + m] <= tks[ik])) m++;
      for (int g = 0; g < m; g += 4) {
        int sl = g + q;
        if (sl < m) {
          int e = eix[ie + sl];
          float eav = eas[ie + sl];
          int s = ei[e], d = ei[NE + e];
          const float* xp = &x[s * DD];
          float A = 0.f, B = 0.f;
#pragma unroll 2
          for (int i = 0; i < DD; i++) {
            float xv = xp[i];
            A = fmaf(xv, Pl[i * 64 + o], A);
            B = fmaf(xv, Ql[i * 64 + o], B);
          }
          atomicAdd(&agg1[d * 64 + o], fmaf(eav, A, B));
        }
      }
      ie += m;
    }
  }
}

// ---------- h = relu(agg/cnt + root + bias) ----------
__global__ __launch_bounds__(256) void k_h(const float* __restrict__ agg,
                                           const float* __restrict__ cnt,
                                           const float* __restrict__ xr,
                                           const float* __restrict__ bc,
                                           float* __restrict__ h) {
  int f = blockIdx.x * 256 + threadIdx.x;  // < 8192
  int n = f >> 6, o = f & 63;
  float c = fmaxf(cnt[n], 1.f);
  h[f] = fmaxf(0.f, agg[f] / c + xr[f] + bc[o]);
}

// ---------- G2[s,k,o] = sum_i h1[s,i] * W2b[k, i*64+o] ----------
__global__ __launch_bounds__(256) void k_g2(const float* __restrict__ h1,
                                            const float* __restrict__ W2b,
                                            float* __restrict__ G2) {
  int f = blockIdx.x * 256 + threadIdx.x;  // < 128*64*64
  int s = f >> 12, k = (f >> 6) & 63, o = f & 63;
  const float* hp = &h1[s * 64];
  const float* wp = &W2b[k * 4096 + o];
  float a = 0.f;
  for (int i = 0; i < 64; i++) a = fmaf(hp[i], wp[i * 64], a);
  G2[f] = a;
}

// ---------- hb2 = h1@B2b, hr2 = h1@Wr2 ----------
__global__ __launch_bounds__(256) void k_small2(const float* __restrict__ h1,
                                                const float* __restrict__ b2b,
                                                const float* __restrict__ Wr2,
                                                float* __restrict__ hb2,
                                                float* __restrict__ hr2) {
  int f = blockIdx.x * 256 + threadIdx.x;  // < 8192
  int n = f >> 6, o = f & 63;
  float a = 0.f, b = 0.f;
  for (int i = 0; i < 64; i++) {
    float hv = h1[n * 64 + i];
    a = fmaf(hv, b2b[i * 64 + o], a);
    b = fmaf(hv, Wr2[i * 64 + o], b);
  }
  hb2[f] = a; hr2[f] = b;
}

// ---------- conv2 per-edge message + scatter ----------
__global__ __launch_bounds__(256) void k_consume2(const float* __restrict__ G2,
                                                  const float* __restrict__ W2a,
                                                  const float* __restrict__ b2a,
                                                  const float* __restrict__ eattr,
                                                  const int* __restrict__ ei,
                                                  const float* __restrict__ hb2,
                                                  float* __restrict__ agg2) {
  __shared__ float wa[64], wb[64];
  int t = threadIdx.x;
  if (t < 64) { wa[t] = W2a[t]; wb[t] = b2a[t]; }
  __syncthreads();
  int f = blockIdx.x * 256 + t;  // < NE*64
  int e = f >> 6, o = f & 63;
  int s = ei[e], d = ei[NE + e];
  float ev = eattr[e];
  float a = hb2[s * 64 + o];
  const float* gp = &G2[s * 4096 + o];
  for (int k = 0; k < 64; k++) {
    float u = fmaxf(0.f, fmaf(ev, wa[k], wb[k]));
    a = fmaf(u, gp[k * 64], a);
  }
  atomicAdd(&agg2[d * 64 + o], a);
}

// ---------- logits -> masked softmax -> packet-mask rows ----------
__global__ __launch_bounds__(128) void k_out(const float* __restrict__ h2,
                                             const float* __restrict__ Wout,
                                             const float* __restrict__ bout,
                                             const int* __restrict__ adj,
                                             const float* __restrict__ npk,
                                             float* __restrict__ out) {
  __shared__ float hs[64];
  __shared__ float redm[2], reds[2];
  int n = blockIdx.x, j = threadIdx.x;
  if (j < 64) hs[j] = h2[n * 64 + j];
  __syncthreads();
  float l = bout[j];
  for (int k = 0; k < 64; k++) l = fmaf(hs[k], Wout[k * 128 + j], l);
  bool am = adj[n * 128 + j] != 0;
  float lm = am ? l : -3.0e38f;
  float m = lm;
  for (int off = 32; off >= 1; off >>= 1) m = fmaxf(m, __shfl_xor(m, off, 64));
  int wid = j >> 6;
  if ((j & 63) == 0) redm[wid] = m;
  __syncthreads();
  m = fmaxf(redm[0], redm[1]);
  float p = am ? expf(lm - m) : 0.f;
  float sv = p;
  for (int off = 32; off >= 1; off >>= 1) sv += __shfl_xor(sv, off, 64);
  if ((j & 63) == 0) reds[wid] = sv;
  __syncthreads();
  sv = reds[0] + reds[1];
  float prob = p / sv;
  bool haspkt = (npk[n] != -1.0f);
  out[n * 128 + j] = haspkt ? prob : ((j == n) ? 1.f : 0.f);
}

extern "C" void kernel_launch(void* const* d_in, const int* in_sizes, int n_in,
                              void* d_out, int out_size, void* d_ws, size_t ws_size,
                              hipStream_t stream) {
  const float* x    = (const float*)d_in[0];
  const int*   ei   = (const int*)  d_in[1];
  const float* ea   = (const float*)d_in[2];
  const int*   adj  = (const int*)  d_in[3];
  const float* npk  = (const float*)d_in[4];
  const float* W1a  = (const float*)d_in[5];
  const float* b1a  = (const float*)d_in[6];
  const float* W1b  = (const float*)d_in[7];
  const float* b1b  = (const float*)d_in[8];
  const float* Wr1  = (const float*)d_in[9];
  const float* bc1  = (const float*)d_in[10];
  const float* W2a  = (const float*)d_in[11];
  const float* b2a  = (const float*)d_in[12];
  const float* W2b  = (const float*)d_in[13];
  const float* b2b  = (const float*)d_in[14];
  const float* Wr2  = (const float*)d_in[15];
  const float* bc2  = (const float*)d_in[16];
  const float* Wout = (const float*)d_in[17];
  const float* bout = (const float*)d_in[18];

  float* ws = (float*)d_ws;
  int*   ip = (int*)(ws + OFF_INT);
  int* e_off = ip;
  int* k_off = ip + 257;
  int* e_idx = ip + 514;
  int* k_idx = ip + 4610;

  hipMemsetAsync(ws, 0, ZERO_F * sizeof(float), stream);
  k_count<<<1, 256, 0, stream>>>(ei, ea, W1a, b1a, e_off, k_off, e_idx, k_idx, ws + OFF_CNT);
  k_small1x<<<32, 256, 0, stream>>>(x, Wr1, ws + OFF_XR1);
  k_build<<<dim3(130, 2), 256, 0, stream>>>(W1a, b1a, W1b, ws + OFF_PD, ws + OFF_QD);
  k_sweep<<<CC, 256, 0, stream>>>(ws + OFF_PD, ws + OFF_QD, b1b, W1a, b1a, W1b,
                                  x, ea, ei, e_off, e_idx, k_off, k_idx, ws + OFF_AGG1);
  k_h<<<32, 256, 0, stream>>>(ws + OFF_AGG1, ws + OFF_CNT, ws + OFF_XR1, bc1, ws + OFF_H1);
  k_g2<<<2048, 256, 0, stream>>>(ws + OFF_H1, W2b, ws + OFF_G2);
  k_small2<<<32, 256, 0, stream>>>(ws + OFF_H1, b2b, Wr2, ws + OFF_HB2, ws + OFF_HR2);
  k_consume2<<<1024, 256, 0, stream>>>(ws + OFF_G2, W2a, b2a, ea, ei, ws + OFF_HB2,
                                       ws + OFF_AGG2);
  k_h<<<32, 256, 0, stream>>>(ws + OFF_AGG2, ws + OFF_CNT, ws + OFF_HR2, bc2, ws + OFF_H2);
  k_out<<<128, 128, 0, stream>>>(ws + OFF_H2, Wout, bout, adj, npk, (float*)d_out);
}

// Round 3
// 650.118 us; speedup vs baseline: 2.3757x; 2.3757x over previous
//
#include <hip/hip_runtime.h>

#define NN 128
#define NE 4096
#define DD 130
#define HH 64
#define KK1 8320   // D*H
#define CC 256     // ea-value chunks

// workspace layout (float offsets)
#define OFF_AGG1 0            // 8192
#define OFF_AGG2 8192         // 8192
#define ZERO_F   16384        // floats zeroed each call (agg1+agg2)
#define OFF_CNT  16384        // 128 (fully written by k_count)
#define OFF_XR1  16512        // 8192
#define OFF_H1   24704        // 8192
#define OFF_HB2  32896        // 8192
#define OFF_HR2  41088        // 8192
#define OFF_H2   49280        // 8192
#define OFF_G2   57472        // 524288 -> ends 581760
#define OFF_SP   581760       // CC*KK1 = 2129920 (chunk-left P states; row 0 = base, atomically built)
#define OFF_SQ   2711680      // CC*KK1
#define OFF_DP   4841600      // CC*KK1 (per-chunk diffs)
#define OFF_DQ   6971520      // CC*KK1 -> ends 9101440
#define OFF_INT  9101440      // ints: e_off[257], k_off[257], e_idx[4096], k_idx[8320], base_idx[8320], nbase[1]

// Event bin for threshold t_k = -c/a within [0,1): chunk in which k flips.
// a>0: activates when ea crosses t upward. a<0: deactivates.
__device__ __forceinline__ int event_bin(float a, float c) {
  if (a > 0.f) {
    if (c <= 0.f) { float tt = -c / a; if (tt < 1.f) return (int)(tt * 256.0f); }
  } else if (a < 0.f) {
    if (c > 0.f) { float tt = -c / a; if (tt < 1.f) return (int)ceilf(tt * 256.0f) - 1; }
  }
  return -1;
}

// ---------- counts, chunk lists for edges / k-events / base rows ----------
__global__ __launch_bounds__(256) void k_count(const int* __restrict__ ei,
                                               const float* __restrict__ eattr,
                                               const float* __restrict__ W1a,
                                               const float* __restrict__ b1a,
                                               int* __restrict__ e_off,
                                               int* __restrict__ k_off,
                                               int* __restrict__ e_idx,
                                               int* __restrict__ k_idx,
                                               int* __restrict__ base_idx,
                                               int* __restrict__ nbase,
                                               float* __restrict__ cnt) {
  __shared__ int ec[CC], kc[CC], cd[NN];
  __shared__ int eo[CC + 1], ko[CC + 1];
  __shared__ int bcnt;
  int t = threadIdx.x;
  ec[t] = 0; kc[t] = 0;
  if (t < NN) cd[t] = 0;
  if (t == 0) bcnt = 0;
  __syncthreads();
  for (int e = t; e < NE; e += 256) {
    atomicAdd(&cd[ei[NE + e]], 1);
    int c = (int)(eattr[e] * 256.0f); c = c < 0 ? 0 : (c > CC - 1 ? CC - 1 : c);
    atomicAdd(&ec[c], 1);
  }
  for (int k = t; k < KK1; k += 256) {
    int b = event_bin(W1a[k], b1a[k]);
    if (b >= 0) atomicAdd(&kc[b], 1);
    if (b1a[k] > 0.f) { int p = atomicAdd(&bcnt, 1); base_idx[p] = k; }
  }
  __syncthreads();
  if (t == 0) {
    *nbase = bcnt;
    int r = 0;
    for (int c = 0; c < CC; c++) { eo[c] = r; r += ec[c]; } eo[CC] = r;
    r = 0;
    for (int c = 0; c < CC; c++) { ko[c] = r; r += kc[c]; } ko[CC] = r;
  }
  __syncthreads();
  if (t < NN) cnt[t] = (float)cd[t];
  e_off[t] = eo[t]; k_off[t] = ko[t];
  if (t == 0) { e_off[CC] = eo[CC]; k_off[CC] = ko[CC]; }
  ec[t] = eo[t]; kc[t] = ko[t];   // cursors
  __syncthreads();
  for (int e = t; e < NE; e += 256) {
    int c = (int)(eattr[e] * 256.0f); c = c < 0 ? 0 : (c > CC - 1 ? CC - 1 : c);
    int p = atomicAdd(&ec[c], 1);
    e_idx[p] = e;
  }
  for (int k = t; k < KK1; k += 256) {
    int b = event_bin(W1a[k], b1a[k]);
    if (b >= 0) { int p = atomicAdd(&kc[b], 1); k_idx[p] = k; }
  }
}

// ---------- xr1 = x @ Wr1 ----------
__global__ __launch_bounds__(256) void k_small1x(const float* __restrict__ x,
                                                 const float* __restrict__ Wr1,
                                                 float* __restrict__ xr1) {
  int f = blockIdx.x * 256 + threadIdx.x;   // < 8192
  int n = f >> 6, o = f & 63;
  float a = 0.f;
  for (int i = 0; i < DD; i++) a = fmaf(x[n * DD + i], Wr1[i * HH + o], a);
  xr1[f] = a;
}

// ---------- base state: SP0/SQ0 += sum over base rows of (a*w, c*w) ----------
// Each block streams full contiguous rows; accumulators live in VGPRs.
#define MCOL 33   // ceil(8320/256)
__global__ __launch_bounds__(256) void k_base(const float* __restrict__ W1a,
                                              const float* __restrict__ b1a,
                                              const float* __restrict__ W1b,
                                              const int* __restrict__ base_idx,
                                              const int* __restrict__ nbase,
                                              float* __restrict__ SP0,
                                              float* __restrict__ SQ0) {
  int t = threadIdx.x;
  int nb = *nbase;
  float rp[MCOL], rq[MCOL];
#pragma unroll
  for (int m = 0; m < MCOL; m++) { rp[m] = 0.f; rq[m] = 0.f; }
  for (int r = blockIdx.x; r < nb; r += gridDim.x) {
    int k = base_idx[r];
    float a = W1a[k], c2 = b1a[k];
    const float* row = &W1b[(long)k * KK1];
#pragma unroll
    for (int m = 0; m < MCOL; m++) {
      int col = t + 256 * m;
      if (col < KK1) {
        float w = row[col];
        rp[m] = fmaf(a, w, rp[m]);
        rq[m] = fmaf(c2, w, rq[m]);
      }
    }
  }
#pragma unroll
  for (int m = 0; m < MCOL; m++) {
    int col = t + 256 * m;
    if (col < KK1) {
      atomicAdd(&SP0[col], rp[m]);
      atomicAdd(&SQ0[col], rq[m]);
    }
  }
}

// ---------- per-chunk diffs: D_c = sum over events in chunk c of (sa*w, sc*w) ----------
__global__ __launch_bounds__(256) void k_diff(const float* __restrict__ W1a,
                                              const float* __restrict__ b1a,
                                              const float* __restrict__ W1b,
                                              const int* __restrict__ k_off,
                                              const int* __restrict__ k_idx,
                                              float* __restrict__ DP,
                                              float* __restrict__ DQ) {
  int c = blockIdx.x, t = threadIdx.x;
  int kb = k_off[c], ke = k_off[c + 1];
  float rp[MCOL], rq[MCOL];
#pragma unroll
  for (int m = 0; m < MCOL; m++) { rp[m] = 0.f; rq[m] = 0.f; }
  for (int r = kb; r < ke; ++r) {
    int k = k_idx[r];
    float a = W1a[k], c2 = b1a[k];
    float sa = (a > 0.f) ? a : -a;
    float sc = (a > 0.f) ? c2 : -c2;
    const float* row = &W1b[(long)k * KK1];
#pragma unroll
    for (int m = 0; m < MCOL; m++) {
      int col = t + 256 * m;
      if (col < KK1) {
        float w = row[col];
        rp[m] = fmaf(sa, w, rp[m]);
        rq[m] = fmaf(sc, w, rq[m]);
      }
    }
  }
#pragma unroll
  for (int m = 0; m < MCOL; m++) {
    int col = t + 256 * m;
    if (col < KK1) {
      DP[(long)c * KK1 + col] = rp[m];
      DQ[(long)c * KK1 + col] = rq[m];
    }
  }
}

// ---------- prefix over chunks: S[c] = S[0] + sum_{c'<c} D[c'] ----------
__global__ __launch_bounds__(256) void k_prefix(float* __restrict__ SP,
                                                float* __restrict__ SQ,
                                                const float* __restrict__ DP,
                                                const float* __restrict__ DQ) {
  int f = blockIdx.x * 256 + threadIdx.x;   // < 2*KK1 (=16640, exact)
  float* S; const float* Dm; int col;
  if (f < KK1) { S = SP; Dm = DP; col = f; }
  else         { S = SQ; Dm = DQ; col = f - KK1; }
  float s = S[col];
  for (int c = 1; c < CC; c++) {
    s += Dm[(long)(c - 1) * KK1 + col];
    S[(long)c * KK1 + col] = s;
  }
}

// ---------- per-chunk sweep: events update P,Q in LDS; edges -> agg1 atomically ----------
#define EC 192
#define KC 128
__global__ __launch_bounds__(256) void k_sweep(const float* __restrict__ SP,
                                               const float* __restrict__ SQ,
                                               const float* __restrict__ b1b,
                                               const float* __restrict__ W1a,
                                               const float* __restrict__ b1a,
                                               const float* __restrict__ W1b,
                                               const float* __restrict__ x,
                                               const float* __restrict__ eattr,
                                               const int* __restrict__ ei,
                                               const int* __restrict__ e_off,
                                               const int* __restrict__ e_idx,
                                               const int* __restrict__ k_off,
                                               const int* __restrict__ k_idx,
                                               float* __restrict__ agg1) {
  __shared__ float Pl[KK1], Ql[KK1];
  __shared__ float eas[EC], eas_r[EC];
  __shared__ int eix[EC], eix_r[EC];
  __shared__ float tks[KC], tks_r[KC];
  __shared__ int kix[KC], kix_r[KC];
  int c = blockIdx.x, t = threadIdx.x;
  int eb = e_off[c], ne = e_off[c + 1] - eb; if (ne > EC) ne = EC;
  int kb = k_off[c], nk = k_off[c + 1] - kb; if (nk > KC) nk = KC;
  for (int j = t; j < KK1; j += 256) {
    Pl[j] = SP[(long)c * KK1 + j];
    Ql[j] = SQ[(long)c * KK1 + j] + b1b[j];
  }
  if (t < ne) { int e = e_idx[eb + t]; eix_r[t] = e; eas_r[t] = eattr[e]; }
  if (t < nk) {
    int k = k_idx[kb + t];
    kix_r[t] = k;
    tks_r[t] = -b1a[k] / W1a[k];
  }
  __syncthreads();
  if (t < ne) {  // rank sort edges by ea
    float key = eas_r[t]; int rk = 0;
    for (int j = 0; j < ne; j++) { float kj = eas_r[j]; rk += (kj < key) || (kj == key && j < t); }
    eas[rk] = key; eix[rk] = eix_r[t];
  }
  if (t < nk) {  // rank sort events by threshold
    float key = tks_r[t]; int rk = 0;
    for (int j = 0; j < nk; j++) { float kj = tks_r[j]; rk += (kj < key) || (kj == key && j < t); }
    tks[rk] = key; kix[rk] = kix_r[t];
  }
  __syncthreads();
  if (ne == 0) return;
  int ie = 0, ik = 0;
  int q = t >> 6, o = t & 63;
  while (ie < ne) {
    if (ik < nk && tks[ik] < eas[ie]) {
      int k = kix[ik];
      float a = W1a[k], c2 = b1a[k];
      float sa = (a > 0.f) ? a : -a;
      float sc = (a > 0.f) ? c2 : -c2;
      __syncthreads();                    // prior batch reads of Pl/Ql complete
      for (int j = t; j < KK1; j += 256) {
        float w = W1b[(long)k * KK1 + j];
        Pl[j] = fmaf(sa, w, Pl[j]);
        Ql[j] = fmaf(sc, w, Ql[j]);
      }
      __syncthreads();
      ik++;
    } else {
      int m = 1;
      while (ie + m < ne && (ik >= nk || eas[ie + m] <= tks[ik])) m++;
      for (int g = 0; g < m; g += 4) {
        int sl = g + q;
        if (sl < m) {
          int e = eix[ie + sl];
          float eav = eas[ie + sl];
          int s = ei[e], d = ei[NE + e];
          const float* xp = &x[s * DD];
          float A = 0.f, B = 0.f;
#pragma unroll 2
          for (int i = 0; i < DD; i++) {
            float xv = xp[i];
            A = fmaf(xv, Pl[i * 64 + o], A);
            B = fmaf(xv, Ql[i * 64 + o], B);
          }
          atomicAdd(&agg1[d * 64 + o], fmaf(eav, A, B));
        }
      }
      ie += m;
    }
  }
}

// ---------- h = relu(agg/cnt + root + bias) ----------
__global__ __launch_bounds__(256) void k_h(const float* __restrict__ agg,
                                           const float* __restrict__ cnt,
                                           const float* __restrict__ xr,
                                           const float* __restrict__ bc,
                                           float* __restrict__ h) {
  int f = blockIdx.x * 256 + threadIdx.x;  // < 8192
  int n = f >> 6, o = f & 63;
  float c = fmaxf(cnt[n], 1.f);
  h[f] = fmaxf(0.f, agg[f] / c + xr[f] + bc[o]);
}

// ---------- G2[s,k,o] = sum_i h1[s,i] * W2b[k, i*64+o] ----------
__global__ __launch_bounds__(256) void k_g2(const float* __restrict__ h1,
                                            const float* __restrict__ W2b,
                                            float* __restrict__ G2) {
  int f = blockIdx.x * 256 + threadIdx.x;  // < 128*64*64
  int s = f >> 12, k = (f >> 6) & 63, o = f & 63;
  const float* hp = &h1[s * 64];
  const float* wp = &W2b[k * 4096 + o];
  float a = 0.f;
  for (int i = 0; i < 64; i++) a = fmaf(hp[i], wp[i * 64], a);
  G2[f] = a;
}

// ---------- hb2 = h1@B2b, hr2 = h1@Wr2 ----------
__global__ __launch_bounds__(256) void k_small2(const float* __restrict__ h1,
                                                const float* __restrict__ b2b,
                                                const float* __restrict__ Wr2,
                                                float* __restrict__ hb2,
                                                float* __restrict__ hr2) {
  int f = blockIdx.x * 256 + threadIdx.x;  // < 8192
  int n = f >> 6, o = f & 63;
  float a = 0.f, b = 0.f;
  for (int i = 0; i < 64; i++) {
    float hv = h1[n * 64 + i];
    a = fmaf(hv, b2b[i * 64 + o], a);
    b = fmaf(hv, Wr2[i * 64 + o], b);
  }
  hb2[f] = a; hr2[f] = b;
}

// ---------- conv2 per-edge message + scatter ----------
__global__ __launch_bounds__(256) void k_consume2(const float* __restrict__ G2,
                                                  const float* __restrict__ W2a,
                                                  const float* __restrict__ b2a,
                                                  const float* __restrict__ eattr,
                                                  const int* __restrict__ ei,
                                                  const float* __restrict__ hb2,
                                                  float* __restrict__ agg2) {
  __shared__ float wa[64], wb[64];
  int t = threadIdx.x;
  if (t < 64) { wa[t] = W2a[t]; wb[t] = b2a[t]; }
  __syncthreads();
  int f = blockIdx.x * 256 + t;  // < NE*64
  int e = f >> 6, o = f & 63;
  int s = ei[e], d = ei[NE + e];
  float ev = eattr[e];
  float a = hb2[s * 64 + o];
  const float* gp = &G2[s * 4096 + o];
  for (int k = 0; k < 64; k++) {
    float u = fmaxf(0.f, fmaf(ev, wa[k], wb[k]));
    a = fmaf(u, gp[k * 64], a);
  }
  atomicAdd(&agg2[d * 64 + o], a);
}

// ---------- logits -> masked softmax -> packet-mask rows ----------
__global__ __launch_bounds__(128) void k_out(const float* __restrict__ h2,
                                             const float* __restrict__ Wout,
                                             const float* __restrict__ bout,
                                             const int* __restrict__ adj,
                                             const float* __restrict__ npk,
                                             float* __restrict__ out) {
  __shared__ float hs[64];
  __shared__ float redm[2], reds[2];
  int n = blockIdx.x, j = threadIdx.x;
  if (j < 64) hs[j] = h2[n * 64 + j];
  __syncthreads();
  float l = bout[j];
  for (int k = 0; k < 64; k++) l = fmaf(hs[k], Wout[k * 128 + j], l);
  bool am = adj[n * 128 + j] != 0;
  float lm = am ? l : -3.0e38f;
  float m = lm;
  for (int off = 32; off >= 1; off >>= 1) m = fmaxf(m, __shfl_xor(m, off, 64));
  int wid = j >> 6;
  if ((j & 63) == 0) redm[wid] = m;
  __syncthreads();
  m = fmaxf(redm[0], redm[1]);
  float p = am ? expf(lm - m) : 0.f;
  float sv = p;
  for (int off = 32; off >= 1; off >>= 1) sv += __shfl_xor(sv, off, 64);
  if ((j & 63) == 0) reds[wid] = sv;
  __syncthreads();
  sv = reds[0] + reds[1];
  float prob = p / sv;
  bool haspkt = (npk[n] != -1.0f);
  out[n * 128 + j] = haspkt ? prob : ((j == n) ? 1.f : 0.f);
}

extern "C" void kernel_launch(void* const* d_in, const int* in_sizes, int n_in,
                              void* d_out, int out_size, void* d_ws, size_t ws_size,
                              hipStream_t stream) {
  const float* x    = (const float*)d_in[0];
  const int*   ei   = (const int*)  d_in[1];
  const float* ea   = (const float*)d_in[2];
  const int*   adj  = (const int*)  d_in[3];
  const float* npk  = (const float*)d_in[4];
  const float* W1a  = (const float*)d_in[5];
  const float* b1a  = (const float*)d_in[6];
  const float* W1b  = (const float*)d_in[7];
  const float* b1b  = (const float*)d_in[8];
  const float* Wr1  = (const float*)d_in[9];
  const float* bc1  = (const float*)d_in[10];
  const float* W2a  = (const float*)d_in[11];
  const float* b2a  = (const float*)d_in[12];
  const float* W2b  = (const float*)d_in[13];
  const float* b2b  = (const float*)d_in[14];
  const float* Wr2  = (const float*)d_in[15];
  const float* bc2  = (const float*)d_in[16];
  const float* Wout = (const float*)d_in[17];
  const float* bout = (const float*)d_in[18];

  float* ws = (float*)d_ws;
  int*   ip = (int*)(ws + OFF_INT);
  int* e_off    = ip;
  int* k_off    = ip + 257;
  int* e_idx    = ip + 514;
  int* k_idx    = ip + 4610;
  int* base_idx = ip + 12930;
  int* nbase    = ip + 21250;

  hipMemsetAsync(ws, 0, ZERO_F * sizeof(float), stream);
  hipMemsetAsync(ws + OFF_SP, 0, KK1 * sizeof(float), stream);   // S_P[0]
  hipMemsetAsync(ws + OFF_SQ, 0, KK1 * sizeof(float), stream);   // S_Q[0]

  k_count<<<1, 256, 0, stream>>>(ei, ea, W1a, b1a, e_off, k_off, e_idx, k_idx,
                                 base_idx, nbase, ws + OFF_CNT);
  k_small1x<<<32, 256, 0, stream>>>(x, Wr1, ws + OFF_XR1);
  k_base<<<256, 256, 0, stream>>>(W1a, b1a, W1b, base_idx, nbase,
                                  ws + OFF_SP, ws + OFF_SQ);
  k_diff<<<CC, 256, 0, stream>>>(W1a, b1a, W1b, k_off, k_idx, ws + OFF_DP, ws + OFF_DQ);
  k_prefix<<<65, 256, 0, stream>>>(ws + OFF_SP, ws + OFF_SQ, ws + OFF_DP, ws + OFF_DQ);
  k_sweep<<<CC, 256, 0, stream>>>(ws + OFF_SP, ws + OFF_SQ, b1b, W1a, b1a, W1b,
                                  x, ea, ei, e_off, e_idx, k_off, k_idx, ws + OFF_AGG1);
  k_h<<<32, 256, 0, stream>>>(ws + OFF_AGG1, ws + OFF_CNT, ws + OFF_XR1, bc1, ws + OFF_H1);
  k_g2<<<2048, 256, 0, stream>>>(ws + OFF_H1, W2b, ws + OFF_G2);
  k_small2<<<32, 256, 0, stream>>>(ws + OFF_H1, b2b, Wr2, ws + OFF_HB2, ws + OFF_HR2);
  k_consume2<<<1024, 256, 0, stream>>>(ws + OFF_G2, W2a, b2a, ea, ei, ws + OFF_HB2,
                                       ws + OFF_AGG2);
  k_h<<<32, 256, 0, stream>>>(ws + OFF_AGG2, ws + OFF_CNT, ws + OFF_HR2, bc2, ws + OFF_H2);
  k_out<<<128, 128, 0, stream>>>(ws + OFF_H2, Wout, bout, adj, npk, (float*)d_out);
}

// Round 4
// 643.902 us; speedup vs baseline: 2.3986x; 1.0097x over previous
//
#include <hip/hip_runtime.h>

#define NN 128
#define NE 4096
#define DD 130
#define HH 64
#define KK1 8320   // D*H
#define CC 256     // ea-value chunks
#define NSEG 16
#define SEGC 16    // chunks per segment

// workspace layout (float offsets)
#define OFF_AGG1 0            // 8192 (zeroed each call; sweep atomics)
#define ZERO_F   8192
#define OFF_CNT  8192         // 128 (fully written by k_count)
#define OFF_XR1  8320         // 8192
#define OFF_H1   16512        // 8192
#define OFF_HB2  24704        // 8192
#define OFF_HR2  32896        // 8192
#define OFF_H2   41088        // 8192
#define OFF_AGG2 49280        // 8192 (fully written by k_consume2)
#define OFF_G2   57472        // 524288 -> ends 581760
#define OFF_SP   581760       // CC*KK1 (chunk-left P states; row 0 = base)
#define OFF_SQ   2711680      // CC*KK1 (row 0 init'd to b1b by k_init)
#define OFF_DP   4841600      // CC*KK1 (per-chunk diffs)
#define OFF_DQ   6971520      // CC*KK1 -> ends 9101440
#define OFF_INT  9101440      // ints, 25600 slots
#define OFF_TP   9127040      // NSEG*KK1 = 133120 (segment sums)
#define OFF_TQ   9260160      // NSEG*KK1 -> ends 9393280

// Event bin for threshold t_k = -c/a within [0,1): chunk in which k flips.
// a>0: activates when ea crosses t upward. a<0: deactivates.
__device__ __forceinline__ int event_bin(float a, float c) {
  if (a > 0.f) {
    if (c <= 0.f) { float tt = -c / a; if (tt < 1.f) return (int)(tt * 256.0f); }
  } else if (a < 0.f) {
    if (c > 0.f) { float tt = -c / a; if (tt < 1.f) return (int)ceilf(tt * 256.0f) - 1; }
  }
  return -1;
}

// ---------- counts, chunk lists for edges / k-events / base rows / dst-CSR ----------
__global__ __launch_bounds__(256) void k_count(const int* __restrict__ ei,
                                               const float* __restrict__ eattr,
                                               const float* __restrict__ W1a,
                                               const float* __restrict__ b1a,
                                               int* __restrict__ e_off,
                                               int* __restrict__ k_off,
                                               int* __restrict__ e_idx,
                                               int* __restrict__ k_idx,
                                               int* __restrict__ base_idx,
                                               int* __restrict__ nbase,
                                               int* __restrict__ d_off,
                                               int* __restrict__ perm_dst,
                                               float* __restrict__ cnt) {
  __shared__ int ec[CC], kc[CC], cd[NN];
  __shared__ int eo[CC + 1], ko[CC + 1], doff[NN + 1];
  __shared__ int bcnt;
  int t = threadIdx.x;
  ec[t] = 0; kc[t] = 0;
  if (t < NN) cd[t] = 0;
  if (t == 0) bcnt = 0;
  __syncthreads();
  for (int e = t; e < NE; e += 256) {
    atomicAdd(&cd[ei[NE + e]], 1);
    int c = (int)(eattr[e] * 256.0f); c = c < 0 ? 0 : (c > CC - 1 ? CC - 1 : c);
    atomicAdd(&ec[c], 1);
  }
  for (int k = t; k < KK1; k += 256) {
    int b = event_bin(W1a[k], b1a[k]);
    if (b >= 0) atomicAdd(&kc[b], 1);
    if (b1a[k] > 0.f) { int p = atomicAdd(&bcnt, 1); base_idx[p] = k; }
  }
  __syncthreads();
  if (t == 0) {
    *nbase = bcnt;
    int r = 0;
    for (int c = 0; c < CC; c++) { eo[c] = r; r += ec[c]; } eo[CC] = r;
    r = 0;
    for (int c = 0; c < CC; c++) { ko[c] = r; r += kc[c]; } ko[CC] = r;
    r = 0;
    for (int n = 0; n < NN; n++) { doff[n] = r; r += cd[n]; } doff[NN] = r;
  }
  __syncthreads();
  if (t < NN) { cnt[t] = (float)cd[t]; d_off[t] = doff[t]; }
  if (t == 0) d_off[NN] = doff[NN];
  e_off[t] = eo[t]; k_off[t] = ko[t];
  if (t == 0) { e_off[CC] = eo[CC]; k_off[CC] = ko[CC]; }
  ec[t] = eo[t]; kc[t] = ko[t];        // cursors
  if (t < NN) cd[t] = doff[t];         // dst cursor
  __syncthreads();
  for (int e = t; e < NE; e += 256) {
    int c = (int)(eattr[e] * 256.0f); c = c < 0 ? 0 : (c > CC - 1 ? CC - 1 : c);
    int p = atomicAdd(&ec[c], 1);
    e_idx[p] = e;
    int d = ei[NE + e];
    int pd = atomicAdd(&cd[d], 1);
    perm_dst[pd] = e;
  }
  for (int k = t; k < KK1; k += 256) {
    int b = event_bin(W1a[k], b1a[k]);
    if (b >= 0) { int p = atomicAdd(&kc[b], 1); k_idx[p] = k; }
  }
}

// ---------- xr1 = x @ Wr1 ----------
__global__ __launch_bounds__(256) void k_small1x(const float* __restrict__ x,
                                                 const float* __restrict__ Wr1,
                                                 float* __restrict__ xr1) {
  int f = blockIdx.x * 256 + threadIdx.x;   // < 8192
  int n = f >> 6, o = f & 63;
  float a = 0.f;
  for (int i = 0; i < DD; i++) a = fmaf(x[n * DD + i], Wr1[i * HH + o], a);
  xr1[f] = a;
}

// ---------- init S row 0: SP0 = 0, SQ0 = b1b (b1b folds through prefix) ----------
__global__ __launch_bounds__(256) void k_init(const float* __restrict__ b1b,
                                              float* __restrict__ SP0,
                                              float* __restrict__ SQ0) {
  int f = blockIdx.x * 256 + threadIdx.x;
  if (f < KK1) { SP0[f] = 0.f; SQ0[f] = b1b[f]; }
}

// ---------- base state: SP0/SQ0 += sum over base rows of (a*w, c*w) ----------
#define MCOL 33   // ceil(8320/256)
__global__ __launch_bounds__(256) void k_base(const float* __restrict__ W1a,
                                              const float* __restrict__ b1a,
                                              const float* __restrict__ W1b,
                                              const int* __restrict__ base_idx,
                                              const int* __restrict__ nbase,
                                              float* __restrict__ SP0,
                                              float* __restrict__ SQ0) {
  int t = threadIdx.x;
  int nb = *nbase;
  float rp[MCOL], rq[MCOL];
#pragma unroll
  for (int m = 0; m < MCOL; m++) { rp[m] = 0.f; rq[m] = 0.f; }
  for (int r = blockIdx.x; r < nb; r += gridDim.x) {
    int k = base_idx[r];
    float a = W1a[k], c2 = b1a[k];
    const float* row = &W1b[(long)k * KK1];
#pragma unroll
    for (int m = 0; m < MCOL; m++) {
      int col = t + 256 * m;
      if (col < KK1) {
        float w = row[col];
        rp[m] = fmaf(a, w, rp[m]);
        rq[m] = fmaf(c2, w, rq[m]);
      }
    }
  }
#pragma unroll
  for (int m = 0; m < MCOL; m++) {
    int col = t + 256 * m;
    if (col < KK1) {
      atomicAdd(&SP0[col], rp[m]);
      atomicAdd(&SQ0[col], rq[m]);
    }
  }
}

// ---------- per-chunk diffs: D_c = sum over events in chunk c of (sa*w, sc*w) ----------
__global__ __launch_bounds__(256) void k_diff(const float* __restrict__ W1a,
                                              const float* __restrict__ b1a,
                                              const float* __restrict__ W1b,
                                              const int* __restrict__ k_off,
                                              const int* __restrict__ k_idx,
                                              float* __restrict__ DP,
                                              float* __restrict__ DQ) {
  int c = blockIdx.x, t = threadIdx.x;
  int kb = k_off[c], ke = k_off[c + 1];
  float rp[MCOL], rq[MCOL];
#pragma unroll
  for (int m = 0; m < MCOL; m++) { rp[m] = 0.f; rq[m] = 0.f; }
  for (int r = kb; r < ke; ++r) {
    int k = k_idx[r];
    float a = W1a[k], c2 = b1a[k];
    float sa = (a > 0.f) ? a : -a;
    float sc = (a > 0.f) ? c2 : -c2;
    const float* row = &W1b[(long)k * KK1];
#pragma unroll
    for (int m = 0; m < MCOL; m++) {
      int col = t + 256 * m;
      if (col < KK1) {
        float w = row[col];
        rp[m] = fmaf(sa, w, rp[m]);
        rq[m] = fmaf(sc, w, rq[m]);
      }
    }
  }
#pragma unroll
  for (int m = 0; m < MCOL; m++) {
    int col = t + 256 * m;
    if (col < KK1) {
      DP[(long)c * KK1 + col] = rp[m];
      DQ[(long)c * KK1 + col] = rq[m];
    }
  }
}

// ---------- segment sums: T[s] = sum of D over the 16 chunks of segment s ----------
__global__ __launch_bounds__(256) void k_seg(const float* __restrict__ DP,
                                             const float* __restrict__ DQ,
                                             float* __restrict__ TP,
                                             float* __restrict__ TQ) {
  int f = blockIdx.x * 256 + threadIdx.x;   // < 2*KK1 = 16640 exact
  int s = blockIdx.y;
  const float* Dm; float* T; int col;
  if (f < KK1) { Dm = DP; T = TP; col = f; }
  else         { Dm = DQ; T = TQ; col = f - KK1; }
  float a = 0.f;
  for (int p = 0; p < SEGC; p++) a += Dm[(long)(s * SEGC + p) * KK1 + col];
  T[(long)s * KK1 + col] = a;
}

// ---------- scan: S[c] = S[0] + prefix(T) + in-segment prefix(D) ----------
__global__ __launch_bounds__(256) void k_scan(float* __restrict__ SP,
                                              float* __restrict__ SQ,
                                              const float* __restrict__ DP,
                                              const float* __restrict__ DQ,
                                              const float* __restrict__ TP,
                                              const float* __restrict__ TQ) {
  int f = blockIdx.x * 256 + threadIdx.x;   // < 16640
  int s = blockIdx.y;
  float* S; const float* Dm; const float* T; int col;
  if (f < KK1) { S = SP; Dm = DP; T = TP; col = f; }
  else         { S = SQ; Dm = DQ; T = TQ; col = f - KK1; }
  float acc = S[col];                       // row 0 (never rewritten)
  for (int sp = 0; sp < s; sp++) acc += T[(long)sp * KK1 + col];
  for (int p = 0; p < SEGC; p++) {
    int c = s * SEGC + p;
    if (c > 0) S[(long)c * KK1 + col] = acc;
    acc += Dm[(long)c * KK1 + col];
  }
}

// ---------- per-chunk sweep (half-width per block): events in LDS, edges -> agg1 ----------
#define EC 192
#define KC 128
#define KHW 4160   // half width: local j = i*32+ol, global col = i*64 + oh*32 + ol
__global__ __launch_bounds__(256) void k_sweep(const float* __restrict__ SP,
                                               const float* __restrict__ SQ,
                                               const float* __restrict__ W1a,
                                               const float* __restrict__ b1a,
                                               const float* __restrict__ W1b,
                                               const float* __restrict__ x,
                                               const float* __restrict__ eattr,
                                               const int* __restrict__ ei,
                                               const int* __restrict__ e_off,
                                               const int* __restrict__ e_idx,
                                               const int* __restrict__ k_off,
                                               const int* __restrict__ k_idx,
                                               float* __restrict__ agg1) {
  __shared__ float Pl[KHW], Ql[KHW];
  __shared__ float eas[EC], eas_r[EC];
  __shared__ int eix[EC], eix_r[EC];
  __shared__ float tks[KC], tks_r[KC];
  __shared__ int kix[KC], kix_r[KC];
  int c = blockIdx.x, oh = blockIdx.y, t = threadIdx.x;
  int ob = oh * 32;
  int eb = e_off[c], ne = e_off[c + 1] - eb; if (ne > EC) ne = EC;
  int kb = k_off[c], nk = k_off[c + 1] - kb; if (nk > KC) nk = KC;
  for (int j = t; j < KHW; j += 256) {
    int i = j >> 5, ol = j & 31;
    long col = (long)c * KK1 + i * 64 + ob + ol;
    Pl[j] = SP[col];
    Ql[j] = SQ[col];
  }
  if (t < ne) { int e = e_idx[eb + t]; eix_r[t] = e; eas_r[t] = eattr[e]; }
  if (t < nk) {
    int k = k_idx[kb + t];
    kix_r[t] = k;
    tks_r[t] = -b1a[k] / W1a[k];
  }
  __syncthreads();
  if (t < ne) {  // rank sort edges by ea
    float key = eas_r[t]; int rk = 0;
    for (int j = 0; j < ne; j++) { float kj = eas_r[j]; rk += (kj < key) || (kj == key && j < t); }
    eas[rk] = key; eix[rk] = eix_r[t];
  }
  if (t < nk) {  // rank sort events by threshold
    float key = tks_r[t]; int rk = 0;
    for (int j = 0; j < nk; j++) { float kj = tks_r[j]; rk += (kj < key) || (kj == key && j < t); }
    tks[rk] = key; kix[rk] = kix_r[t];
  }
  __syncthreads();
  if (ne == 0) return;
  int ie = 0, ik = 0;
  int q = t >> 5, ol = t & 31;
  while (ie < ne) {
    if (ik < nk && tks[ik] < eas[ie]) {
      int k = kix[ik];
      float a = W1a[k], c2 = b1a[k];
      float sa = (a > 0.f) ? a : -a;
      float sc = (a > 0.f) ? c2 : -c2;
      const float* row = &W1b[(long)k * KK1 + ob];
      __syncthreads();                    // prior batch reads of Pl/Ql complete
      for (int j = t; j < KHW; j += 256) {
        int i = j >> 5, o2 = j & 31;
        float w = row[i * 64 + o2];
        Pl[j] = fmaf(sa, w, Pl[j]);
        Ql[j] = fmaf(sc, w, Ql[j]);
      }
      __syncthreads();
      ik++;
    } else {
      int m = 1;
      while (ie + m < ne && (ik >= nk || eas[ie + m] <= tks[ik])) m++;
      for (int g = 0; g < m; g += 8) {
        int sl = g + q;
        if (sl < m) {
          int e = eix[ie + sl];
          float eav = eas[ie + sl];
          int s = ei[e], d = ei[NE + e];
          const float* xp = &x[s * DD];
          float A = 0.f, B = 0.f;
#pragma unroll 2
          for (int i = 0; i < DD; i++) {
            float xv = xp[i];
            A = fmaf(xv, Pl[i * 32 + ol], A);
            B = fmaf(xv, Ql[i * 32 + ol], B);
          }
          atomicAdd(&agg1[d * 64 + ob + ol], fmaf(eav, A, B));
        }
      }
      ie += m;
    }
  }
}

// ---------- h = relu(agg/cnt + root + bias) ----------
__global__ __launch_bounds__(256) void k_h(const float* __restrict__ agg,
                                           const float* __restrict__ cnt,
                                           const float* __restrict__ xr,
                                           const float* __restrict__ bc,
                                           float* __restrict__ h) {
  int f = blockIdx.x * 256 + threadIdx.x;  // < 8192
  int n = f >> 6, o = f & 63;
  float c = fmaxf(cnt[n], 1.f);
  h[f] = fmaxf(0.f, agg[f] / c + xr[f] + bc[o]);
}

// ---------- G2[s,k,o] = sum_i h1[s,i] * W2b[k, i*64+o] ----------
__global__ __launch_bounds__(256) void k_g2(const float* __restrict__ h1,
                                            const float* __restrict__ W2b,
                                            float* __restrict__ G2) {
  int f = blockIdx.x * 256 + threadIdx.x;  // < 128*64*64
  int s = f >> 12, k = (f >> 6) & 63, o = f & 63;
  const float* hp = &h1[s * 64];
  const float* wp = &W2b[k * 4096 + o];
  float a = 0.f;
  for (int i = 0; i < 64; i++) a = fmaf(hp[i], wp[i * 64], a);
  G2[f] = a;
}

// ---------- hb2 = h1@B2b, hr2 = h1@Wr2 ----------
__global__ __launch_bounds__(256) void k_small2(const float* __restrict__ h1,
                                                const float* __restrict__ b2b,
                                                const float* __restrict__ Wr2,
                                                float* __restrict__ hb2,
                                                float* __restrict__ hr2) {
  int f = blockIdx.x * 256 + threadIdx.x;  // < 8192
  int n = f >> 6, o = f & 63;
  float a = 0.f, b = 0.f;
  for (int i = 0; i < 64; i++) {
    float hv = h1[n * 64 + i];
    a = fmaf(hv, b2b[i * 64 + o], a);
    b = fmaf(hv, Wr2[i * 64 + o], b);
  }
  hb2[f] = a; hr2[f] = b;
}

// ---------- conv2: dst-gather (CSR), no atomics; agg2 fully written ----------
__global__ __launch_bounds__(256) void k_consume2(const float* __restrict__ G2,
                                                  const float* __restrict__ W2a,
                                                  const float* __restrict__ b2a,
                                                  const float* __restrict__ eattr,
                                                  const int* __restrict__ ei,
                                                  const int* __restrict__ d_off,
                                                  const int* __restrict__ perm_dst,
                                                  const float* __restrict__ hb2,
                                                  float* __restrict__ agg2) {
  __shared__ float wa[64], wb[64];
  __shared__ float red[8][32];
  int n = blockIdx.x, oh = blockIdx.y, t = threadIdx.x;
  int sl = t >> 5, ol = t & 31;
  if (t < 64) { wa[t] = W2a[t]; wb[t] = b2a[t]; }
  __syncthreads();
  int b0 = d_off[n], b1 = d_off[n + 1];
  float acc = 0.f;
  for (int r = b0 + sl; r < b1; r += 8) {
    int e = perm_dst[r];
    int s = ei[e];
    float ev = eattr[e];
    const float* gp = &G2[s * 4096 + oh * 32 + ol];
    float a = hb2[s * 64 + oh * 32 + ol];
    for (int k = 0; k < 64; k++) {
      float u = fmaxf(0.f, fmaf(ev, wa[k], wb[k]));
      a = fmaf(u, gp[k * 64], a);
    }
    acc += a;
  }
  red[sl][ol] = acc;
  __syncthreads();
  if (sl == 0) {
    float a = 0.f;
#pragma unroll
    for (int j = 0; j < 8; j++) a += red[j][ol];
    agg2[n * 64 + oh * 32 + ol] = a;
  }
}

// ---------- logits -> masked softmax -> packet-mask rows ----------
__global__ __launch_bounds__(128) void k_out(const float* __restrict__ h2,
                                             const float* __restrict__ Wout,
                                             const float* __restrict__ bout,
                                             const int* __restrict__ adj,
                                             const float* __restrict__ npk,
                                             float* __restrict__ out) {
  __shared__ float hs[64];
  __shared__ float redm[2], reds[2];
  int n = blockIdx.x, j = threadIdx.x;
  if (j < 64) hs[j] = h2[n * 64 + j];
  __syncthreads();
  float l = bout[j];
  for (int k = 0; k < 64; k++) l = fmaf(hs[k], Wout[k * 128 + j], l);
  bool am = adj[n * 128 + j] != 0;
  float lm = am ? l : -3.0e38f;
  float m = lm;
  for (int off = 32; off >= 1; off >>= 1) m = fmaxf(m, __shfl_xor(m, off, 64));
  int wid = j >> 6;
  if ((j & 63) == 0) redm[wid] = m;
  __syncthreads();
  m = fmaxf(redm[0], redm[1]);
  float p = am ? expf(lm - m) : 0.f;
  float sv = p;
  for (int off = 32; off >= 1; off >>= 1) sv += __shfl_xor(sv, off, 64);
  if ((j & 63) == 0) reds[wid] = sv;
  __syncthreads();
  sv = reds[0] + reds[1];
  float prob = p / sv;
  bool haspkt = (npk[n] != -1.0f);
  out[n * 128 + j] = haspkt ? prob : ((j == n) ? 1.f : 0.f);
}

extern "C" void kernel_launch(void* const* d_in, const int* in_sizes, int n_in,
                              void* d_out, int out_size, void* d_ws, size_t ws_size,
                              hipStream_t stream) {
  const float* x    = (const float*)d_in[0];
  const int*   ei   = (const int*)  d_in[1];
  const float* ea   = (const float*)d_in[2];
  const int*   adj  = (const int*)  d_in[3];
  const float* npk  = (const float*)d_in[4];
  const float* W1a  = (const float*)d_in[5];
  const float* b1a  = (const float*)d_in[6];
  const float* W1b  = (const float*)d_in[7];
  const float* b1b  = (const float*)d_in[8];
  const float* Wr1  = (const float*)d_in[9];
  const float* bc1  = (const float*)d_in[10];
  const float* W2a  = (const float*)d_in[11];
  const float* b2a  = (const float*)d_in[12];
  const float* W2b  = (const float*)d_in[13];
  const float* b2b  = (const float*)d_in[14];
  const float* Wr2  = (const float*)d_in[15];
  const float* bc2  = (const float*)d_in[16];
  const float* Wout = (const float*)d_in[17];
  const float* bout = (const float*)d_in[18];

  float* ws = (float*)d_ws;
  int*   ip = (int*)(ws + OFF_INT);
  int* e_off    = ip;
  int* k_off    = ip + 257;
  int* e_idx    = ip + 514;
  int* k_idx    = ip + 4610;
  int* base_idx = ip + 12930;
  int* nbase    = ip + 21250;
  int* d_off    = ip + 21251;
  int* perm_dst = ip + 21380;

  hipMemsetAsync(ws + OFF_AGG1, 0, 8192 * sizeof(float), stream);

  k_count<<<1, 256, 0, stream>>>(ei, ea, W1a, b1a, e_off, k_off, e_idx, k_idx,
                                 base_idx, nbase, d_off, perm_dst, ws + OFF_CNT);
  k_small1x<<<32, 256, 0, stream>>>(x, Wr1, ws + OFF_XR1);
  k_init<<<33, 256, 0, stream>>>(b1b, ws + OFF_SP, ws + OFF_SQ);
  k_base<<<256, 256, 0, stream>>>(W1a, b1a, W1b, base_idx, nbase,
                                  ws + OFF_SP, ws + OFF_SQ);
  k_diff<<<CC, 256, 0, stream>>>(W1a, b1a, W1b, k_off, k_idx, ws + OFF_DP, ws + OFF_DQ);
  k_seg<<<dim3(65, NSEG), 256, 0, stream>>>(ws + OFF_DP, ws + OFF_DQ,
                                            ws + OFF_TP, ws + OFF_TQ);
  k_scan<<<dim3(65, NSEG), 256, 0, stream>>>(ws + OFF_SP, ws + OFF_SQ,
                                             ws + OFF_DP, ws + OFF_DQ,
                                             ws + OFF_TP, ws + OFF_TQ);
  k_sweep<<<dim3(CC, 2), 256, 0, stream>>>(ws + OFF_SP, ws + OFF_SQ, W1a, b1a, W1b,
                                           x, ea, ei, e_off, e_idx, k_off, k_idx,
                                           ws + OFF_AGG1);
  k_h<<<32, 256, 0, stream>>>(ws + OFF_AGG1, ws + OFF_CNT, ws + OFF_XR1, bc1, ws + OFF_H1);
  k_g2<<<2048, 256, 0, stream>>>(ws + OFF_H1, W2b, ws + OFF_G2);
  k_small2<<<32, 256, 0, stream>>>(ws + OFF_H1, b2b, Wr2, ws + OFF_HB2, ws + OFF_HR2);
  k_consume2<<<dim3(NN, 2), 256, 0, stream>>>(ws + OFF_G2, W2a, b2a, ea, ei,
                                              d_off, perm_dst, ws + OFF_HB2,
                                              ws + OFF_AGG2);
  k_h<<<32, 256, 0, stream>>>(ws + OFF_AGG2, ws + OFF_CNT, ws + OFF_HR2, bc2, ws + OFF_H2);
  k_out<<<128, 128, 0, stream>>>(ws + OFF_H2, Wout, bout, adj, npk, (float*)d_out);
}